// Round 20
// baseline (195.997 us; speedup 1.0000x reference)
//
#include <hip/hip_runtime.h>
#include <hip/hip_bf16.h>

typedef __attribute__((ext_vector_type(8))) short s8v;   // 8 x bf16 MFMA operand
typedef __attribute__((ext_vector_type(4))) float f4v;   // MFMA accumulator
typedef __attribute__((ext_vector_type(4))) unsigned short us4;
typedef unsigned short u16;

__device__ __forceinline__ u16 f2bf(float f) {
  union { float f; unsigned int u; } x;
  x.f = f;
  unsigned int lsb = (x.u >> 16) & 1u;
  return (u16)((x.u + 0x7fffu + lsb) >> 16);
}

__device__ __forceinline__ uint4 pack8(float4 a, float4 b) {
  union { u16 u[8]; uint4 v; } t;
  t.u[0] = f2bf(a.x); t.u[1] = f2bf(a.y); t.u[2] = f2bf(a.z); t.u[3] = f2bf(a.w);
  t.u[4] = f2bf(b.x); t.u[5] = f2bf(b.y); t.u[6] = f2bf(b.z); t.u[7] = f2bf(b.w);
  return t.v;
}

// ---------------------------------------------------------------------------
// Kernel 1: projections (r5-identical). C[16384x256] = A[16384x512]@W[512x256]
// ---------------------------------------------------------------------------
__global__ __launch_bounds__(256) void proj_kernel(
    const float* __restrict__ inputs, const float* __restrict__ memory,
    const float* __restrict__ Wq, const float* __restrict__ Wk,
    u16* __restrict__ qb, u16* __restrict__ krow, u16* __restrict__ kcol)
{
  __shared__ u16 Wt[64 * 264];
  __shared__ u16 At[64 * 40];

  const int tid = threadIdx.x;
  const int w = tid >> 6;
  const int l = tid & 63;
  const int lr = l & 15;
  const int lh = l >> 4;
  const int rbase = blockIdx.x * 64;
  const int n0 = blockIdx.y * 64;
  const int src = blockIdx.z;
  const float* __restrict__ A  = src ? memory : inputs;
  const float* __restrict__ Wg = src ? Wk : Wq;

  f4v acc[4];
#pragma unroll
  for (int i = 0; i < 4; ++i) acc[i] = f4v{0.f, 0.f, 0.f, 0.f};

  for (int kh = 0; kh < 2; ++kh) {
    {
      const int kl = tid >> 3;
      const int nl = (tid & 7) * 8;
#pragma unroll
      for (int i = 0; i < 8; ++i) {
        const int k = kl + i * 32;
        const float* s = Wg + (size_t)(kh * 256 + k) * 256 + n0 + nl;
        float4 x0 = *(const float4*)s;
        float4 x1 = *(const float4*)(s + 4);
        Wt[(nl + 0) * 264 + k] = f2bf(x0.x);
        Wt[(nl + 1) * 264 + k] = f2bf(x0.y);
        Wt[(nl + 2) * 264 + k] = f2bf(x0.z);
        Wt[(nl + 3) * 264 + k] = f2bf(x0.w);
        Wt[(nl + 4) * 264 + k] = f2bf(x1.x);
        Wt[(nl + 5) * 264 + k] = f2bf(x1.y);
        Wt[(nl + 6) * 264 + k] = f2bf(x1.z);
        Wt[(nl + 7) * 264 + k] = f2bf(x1.w);
      }
    }
    __syncthreads();
    for (int ks = 0; ks < 8; ++ks) {
      {
        const int row = tid >> 2;
        const int kk = (tid & 3) * 8;
        const float* s = A + (size_t)(rbase + row) * 512 + kh * 256 + ks * 32 + kk;
        float4 x0 = *(const float4*)s;
        float4 x1 = *(const float4*)(s + 4);
        *(uint4*)&At[row * 40 + kk] = pack8(x0, x1);
      }
      __syncthreads();
      const s8v af = *(const s8v*)&At[(w * 16 + lr) * 40 + lh * 8];
#pragma unroll
      for (int nt = 0; nt < 4; ++nt) {
        const s8v bf = *(const s8v*)&Wt[(nt * 16 + lr) * 264 + ks * 32 + lh * 8];
        acc[nt] = __builtin_amdgcn_mfma_f32_16x16x32_bf16(af, bf, acc[nt], 0, 0, 0);
      }
      __syncthreads();
    }
  }

  u16* __restrict__ dst = src ? krow : qb;
#pragma unroll
  for (int nt = 0; nt < 4; ++nt) {
    const int col = n0 + nt * 16 + lr;
    const int R0 = rbase + w * 16 + lh * 4;
    u16 u0 = f2bf(acc[nt][0]);
    u16 u1 = f2bf(acc[nt][1]);
    u16 u2 = f2bf(acc[nt][2]);
    u16 u3 = f2bf(acc[nt][3]);
    dst[(size_t)(R0 + 0) * 256 + col] = u0;
    dst[(size_t)(R0 + 1) * 256 + col] = u1;
    dst[(size_t)(R0 + 2) * 256 + col] = u2;
    dst[(size_t)(R0 + 3) * 256 + col] = u3;
    if (src) {
      const int bb = R0 >> 11;
      const int mm = R0 & 2047;
      us4 pk;
      pk[0] = u0; pk[1] = u1; pk[2] = u2; pk[3] = u3;
      *(us4*)&kcol[((size_t)bb * 256 + col) * 2048 + mm] = pk;
    }
  }
}

// ---------------------------------------------------------------------------
// Kernel 2: row-sum pass (r19-identical: z=8, grid 2048, XCD pin b = bid&7).
// ---------------------------------------------------------------------------
__global__ __launch_bounds__(256) void attn_sum_kernel(
    const u16* __restrict__ qb, const u16* __restrict__ krow,
    const int* __restrict__ mlens, const int* __restrict__ qlens,
    float* __restrict__ psum_p)
{
  __shared__ u16 kr[32 * 264];

  const int tid = threadIdx.x;
  const int w = tid >> 6;
  const int l = tid & 63;
  const int lr = l & 15;
  const int lh = l >> 4;
  const int bid = blockIdx.x;
  const int b = bid & 7;                    // XCD pin
  const int q0 = ((bid >> 3) & 31) * 64;
  const int ms = bid >> 8;                  // 0..7
  const int m_base = ms * 256;
  const int mlen = mlens[b];
  const int qlen = qlens[b];
  const int qrow0 = q0 + w * 16 + lh * 4;

  s8v qf[8];
  {
    const u16* qp = qb + ((size_t)b * 2048 + q0 + w * 16 + lr) * 256 + lh * 8;
#pragma unroll
    for (int s = 0; s < 8; ++s) qf[s] = *(const s8v*)(qp + s * 32);
  }

  float psum[4] = {0.f, 0.f, 0.f, 0.f};
  const float C2 = 0.09016844005556021f;  // log2(e)/16

  for (int mo = 0; mo < 256; mo += 32) {
    const int m0 = m_base + mo;
#pragma unroll
    for (int i = 0; i < 4; ++i) {
      const int idx = i * 256 + tid;
      const int m = idx >> 5, G = idx & 31;
      uint4 v = *(const uint4*)(krow + (((size_t)b * 2048 + m0 + m) << 8) + G * 8);
      *(uint4*)&kr[m * 264 + G * 8] = v;
    }
    __syncthreads();

    f4v sacc[2];
    sacc[0] = f4v{0.f, 0.f, 0.f, 0.f};
    sacc[1] = f4v{0.f, 0.f, 0.f, 0.f};
#pragma unroll
    for (int s = 0; s < 8; ++s) {
#pragma unroll
      for (int f = 0; f < 2; ++f) {
        const s8v bf = *(const s8v*)&kr[(f * 16 + lr) * 264 + s * 32 + lh * 8];
        sacc[f] = __builtin_amdgcn_mfma_f32_16x16x32_bf16(qf[s], bf, sacc[f], 0, 0, 0);
      }
    }
#pragma unroll
    for (int f = 0; f < 2; ++f) {
      const int m = m0 + f * 16 + lr;
      const bool vm = m < mlen;
#pragma unroll
      for (int r = 0; r < 4; ++r) {
        float p = exp2f(sacc[f][r] * C2);
        if (!vm) p = 0.f;
        if (qrow0 + r >= qlen) p = 1.f;
        psum[r] += p;
      }
    }
    __syncthreads();
  }

#pragma unroll
  for (int r = 0; r < 4; ++r) {
    float v = psum[r];
    v += __shfl_xor(v, 1);
    v += __shfl_xor(v, 2);
    v += __shfl_xor(v, 4);
    v += __shfl_xor(v, 8);
    psum[r] = v;
  }
  if (lr == 0) {
#pragma unroll
    for (int r = 0; r < 4; ++r)
      psum_p[ms * 16384 + b * 2048 + qrow0 + r] = psum[r];
  }
}

// ---------------------------------------------------------------------------
// Kernel 3: write pass, 512 threads (8 waves) per block: one staged 32-m tile
// serves 128 q rows. Per-thread state unchanged vs r13 (VGPR ~92). z=4,
// grid 512 = 2 blocks/CU = 16 waves/CU. XCD pin b = bid&7.
// ctx partials: mh=0 -> out_ctx, 1..3 -> octx_ws.
// ---------------------------------------------------------------------------
__global__ __launch_bounds__(512, 4) void attn_wr_kernel(
    const u16* __restrict__ qb, const u16* __restrict__ krow,
    const u16* __restrict__ kcol, const int* __restrict__ mlens,
    const int* __restrict__ qlens, const float* __restrict__ psum_p,
    float* __restrict__ out_align, float* __restrict__ out_ctx,
    float* __restrict__ octx_ws)
{
  __shared__ u16 kr[32 * 264];    // 16896 B
  __shared__ u16 kc[256 * 40];    // 20480 B
  __shared__ u16 pl[8 * 16 * 40]; // 10240 B -> 47.6 KB
  const int tid = threadIdx.x;
  const int w = tid >> 6;          // 0..7
  const int l = tid & 63;
  const int lr = l & 15;
  const int lh = l >> 4;
  const int bid = blockIdx.x;
  const int b = bid & 7;                    // XCD pin
  const int q0 = ((bid >> 3) & 15) * 128;   // 128 q rows per block
  const int mh = bid >> 7;                  // 0..3
  const int m_base = mh * 512;
  const int mlen = mlens[b];
  const int qlen = qlens[b];
  const int qrow0 = q0 + w * 16 + lh * 4;

  s8v qf[8];
  {
    const u16* qp = qb + ((size_t)b * 2048 + q0 + w * 16 + lr) * 256 + lh * 8;
#pragma unroll
    for (int s = 0; s < 8; ++s) qf[s] = *(const s8v*)(qp + s * 32);
  }

  float inv[4];
#pragma unroll
  for (int r = 0; r < 4; ++r) {
    const int q = b * 2048 + qrow0 + r;
    float s = 0.f;
#pragma unroll
    for (int j = 0; j < 8; ++j) s += psum_p[j * 16384 + q];
    inv[r] = 1.0f / s;
  }

  f4v oacc[16];
#pragma unroll
  for (int i = 0; i < 16; ++i) oacc[i] = f4v{0.f, 0.f, 0.f, 0.f};

  const float C2 = 0.09016844005556021f;  // log2(e)/16

  for (int mo = 0; mo < 512; mo += 32) {
    const int m0 = m_base + mo;
    // stage K [32 m][256 a] + V [256 a][32 m]: 1024+1024 granules / 512 thr
#pragma unroll
    for (int i = 0; i < 2; ++i) {
      const int idx = i * 512 + tid;
      const int m = idx >> 5, G = idx & 31;
      uint4 v = *(const uint4*)(krow + (((size_t)b * 2048 + m0 + m) << 8) + G * 8);
      *(uint4*)&kr[m * 264 + G * 8] = v;
      const int a2 = idx >> 2, gm = idx & 3;
      uint4 v2 = *(const uint4*)(kcol + (((size_t)b * 256 + a2) << 11) + m0 + gm * 8);
      *(uint4*)&kc[a2 * 40 + gm * 8] = v2;
    }
    __syncthreads();

    f4v sacc[2];
    sacc[0] = f4v{0.f, 0.f, 0.f, 0.f};
    sacc[1] = f4v{0.f, 0.f, 0.f, 0.f};
#pragma unroll
    for (int s = 0; s < 8; ++s) {
#pragma unroll
      for (int f = 0; f < 2; ++f) {
        const s8v bf = *(const s8v*)&kr[(f * 16 + lr) * 264 + s * 32 + lh * 8];
        sacc[f] = __builtin_amdgcn_mfma_f32_16x16x32_bf16(qf[s], bf, sacc[f], 0, 0, 0);
      }
    }

#pragma unroll
    for (int f = 0; f < 2; ++f) {
      const int m = m0 + f * 16 + lr;
      const bool vm = m < mlen;
#pragma unroll
      for (int r = 0; r < 4; ++r) {
        const int q = qrow0 + r;
        float p = exp2f(sacc[f][r] * C2);
        if (!vm) p = 0.f;
        if (q >= qlen) p = 1.f;
        const float pn = p * inv[r];
        __builtin_nontemporal_store(pn, &out_align[((size_t)b * 2048 + q) * 2048 + m]);
        pl[w * 640 + (lh * 4 + r) * 40 + f * 16 + lr] = f2bf(pn);
      }
    }

    const s8v pa = *(const s8v*)&pl[w * 640 + lr * 40 + lh * 8];
#pragma unroll
    for (int at = 0; at < 16; ++at) {
      const s8v vf = *(const s8v*)&kc[(at * 16 + lr) * 40 + lh * 8];
      oacc[at] = __builtin_amdgcn_mfma_f32_16x16x32_bf16(pa, vf, oacc[at], 0, 0, 0);
    }
    __syncthreads();
  }

  float* __restrict__ dst = (mh == 0) ? out_ctx : (octx_ws + (size_t)(mh - 1) * 4194304);
#pragma unroll
  for (int at = 0; at < 16; ++at) {
    const int a = at * 16 + lr;
#pragma unroll
    for (int r = 0; r < 4; ++r) {
      __builtin_nontemporal_store(oacc[at][r],
          &dst[((size_t)b * 2048 + qrow0 + r) * 256 + a]);
    }
  }
}

// ---------------------------------------------------------------------------
// Kernel 4: out_ctx += octx_ws[0..2]
// ---------------------------------------------------------------------------
__global__ __launch_bounds__(256) void combine_kernel(
    float* __restrict__ out_ctx, const float* __restrict__ octx_ws)
{
  const size_t i = (size_t)blockIdx.x * 256 + threadIdx.x;
  float4 a = ((const float4*)out_ctx)[i];
  float4 c0 = ((const float4*)octx_ws)[i];
  float4 c1 = ((const float4*)(octx_ws + 4194304))[i];
  float4 c2 = ((const float4*)(octx_ws + 8388608))[i];
  a.x += c0.x + c1.x + c2.x;
  a.y += c0.y + c1.y + c2.y;
  a.z += c0.z + c1.z + c2.z;
  a.w += c0.w + c1.w + c2.w;
  ((float4*)out_ctx)[i] = a;
}

extern "C" void kernel_launch(void* const* d_in, const int* in_sizes, int n_in,
                              void* d_out, int out_size, void* d_ws, size_t ws_size,
                              hipStream_t stream) {
  const float* inputs = (const float*)d_in[0];   // [8,2048,512]
  const float* memory = (const float*)d_in[1];   // [8,2048,512]
  const int* mlens    = (const int*)d_in[2];     // [8]
  const int* qlens    = (const int*)d_in[3];     // [8]
  const float* Wq     = (const float*)d_in[4];   // [512,256]
  const float* Wk     = (const float*)d_in[5];   // [512,256]
  (void)in_sizes; (void)n_in; (void)out_size; (void)ws_size;

  u16* wsu = (u16*)d_ws;
  u16* qb   = wsu;                        // 4194304 u16 (8 MB)
  u16* krow = wsu + 4194304;              // 4194304 u16 (8 MB)
  u16* kcol = wsu + 8388608;              // 4194304 u16 (8 MB)
  float* psum_p = (float*)(wsu + 12582912);   // 8*16384 f32 (512 KB)
  float* octx_ws = (float*)(wsu + 12845056);  // 3*4194304 f32 (50.3 MB)

  float* out_ctx = (float*)d_out;             // [8,2048,256]
  float* out_align = out_ctx + 4194304;       // [8,2048,2048]

  proj_kernel<<<dim3(256, 4, 2), dim3(256), 0, stream>>>(
      inputs, memory, Wq, Wk, qb, krow, kcol);
  attn_sum_kernel<<<dim3(2048), dim3(256), 0, stream>>>(
      qb, krow, mlens, qlens, psum_p);
  attn_wr_kernel<<<dim3(512), dim3(512), 0, stream>>>(
      qb, krow, kcol, mlens, qlens, psum_p, out_align, out_ctx, octx_ws);
  combine_kernel<<<dim3(4096), dim3(256), 0, stream>>>(out_ctx, octx_ws);
}

// Round 23
// 170.848 us; speedup vs baseline: 1.1472x; 1.1472x over previous
//
#include <hip/hip_runtime.h>
#include <hip/hip_bf16.h>

typedef __attribute__((ext_vector_type(8))) short s8v;   // 8 x bf16 MFMA operand
typedef __attribute__((ext_vector_type(4))) float f4v;   // MFMA accumulator
typedef __attribute__((ext_vector_type(4))) unsigned short us4;
typedef unsigned short u16;

__device__ __forceinline__ u16 f2bf(float f) {
  union { float f; unsigned int u; } x;
  x.f = f;
  unsigned int lsb = (x.u >> 16) & 1u;
  return (u16)((x.u + 0x7fffu + lsb) >> 16);
}

__device__ __forceinline__ uint4 pack8(float4 a, float4 b) {
  union { u16 u[8]; uint4 v; } t;
  t.u[0] = f2bf(a.x); t.u[1] = f2bf(a.y); t.u[2] = f2bf(a.z); t.u[3] = f2bf(a.w);
  t.u[4] = f2bf(b.x); t.u[5] = f2bf(b.y); t.u[6] = f2bf(b.z); t.u[7] = f2bf(b.w);
  return t.v;
}

// ---------------------------------------------------------------------------
// Kernel 1: projections. C[16384x256] = A[16384x512]@W[512x256], bf16 out.
// src=0: queries -> qb row-major; src=1: keys -> krow row-major + kcol [b][a][m]
// ---------------------------------------------------------------------------
__global__ __launch_bounds__(256) void proj_kernel(
    const float* __restrict__ inputs, const float* __restrict__ memory,
    const float* __restrict__ Wq, const float* __restrict__ Wk,
    u16* __restrict__ qb, u16* __restrict__ krow, u16* __restrict__ kcol)
{
  __shared__ u16 Wt[64 * 264];
  __shared__ u16 At[64 * 40];

  const int tid = threadIdx.x;
  const int w = tid >> 6;
  const int l = tid & 63;
  const int lr = l & 15;
  const int lh = l >> 4;
  const int rbase = blockIdx.x * 64;
  const int n0 = blockIdx.y * 64;
  const int src = blockIdx.z;
  const float* __restrict__ A  = src ? memory : inputs;
  const float* __restrict__ Wg = src ? Wk : Wq;

  f4v acc[4];
#pragma unroll
  for (int i = 0; i < 4; ++i) acc[i] = f4v{0.f, 0.f, 0.f, 0.f};

  for (int kh = 0; kh < 2; ++kh) {
    {
      const int kl = tid >> 3;
      const int nl = (tid & 7) * 8;
#pragma unroll
      for (int i = 0; i < 8; ++i) {
        const int k = kl + i * 32;
        const float* s = Wg + (size_t)(kh * 256 + k) * 256 + n0 + nl;
        float4 x0 = *(const float4*)s;
        float4 x1 = *(const float4*)(s + 4);
        Wt[(nl + 0) * 264 + k] = f2bf(x0.x);
        Wt[(nl + 1) * 264 + k] = f2bf(x0.y);
        Wt[(nl + 2) * 264 + k] = f2bf(x0.z);
        Wt[(nl + 3) * 264 + k] = f2bf(x0.w);
        Wt[(nl + 4) * 264 + k] = f2bf(x1.x);
        Wt[(nl + 5) * 264 + k] = f2bf(x1.y);
        Wt[(nl + 6) * 264 + k] = f2bf(x1.z);
        Wt[(nl + 7) * 264 + k] = f2bf(x1.w);
      }
    }
    __syncthreads();
    for (int ks = 0; ks < 8; ++ks) {
      {
        const int row = tid >> 2;
        const int kk = (tid & 3) * 8;
        const float* s = A + (size_t)(rbase + row) * 512 + kh * 256 + ks * 32 + kk;
        float4 x0 = *(const float4*)s;
        float4 x1 = *(const float4*)(s + 4);
        *(uint4*)&At[row * 40 + kk] = pack8(x0, x1);
      }
      __syncthreads();
      const s8v af = *(const s8v*)&At[(w * 16 + lr) * 40 + lh * 8];
#pragma unroll
      for (int nt = 0; nt < 4; ++nt) {
        const s8v bf = *(const s8v*)&Wt[(nt * 16 + lr) * 264 + ks * 32 + lh * 8];
        acc[nt] = __builtin_amdgcn_mfma_f32_16x16x32_bf16(af, bf, acc[nt], 0, 0, 0);
      }
      __syncthreads();
    }
  }

  u16* __restrict__ dst = src ? krow : qb;
#pragma unroll
  for (int nt = 0; nt < 4; ++nt) {
    const int col = n0 + nt * 16 + lr;
    const int R0 = rbase + w * 16 + lh * 4;
    u16 u0 = f2bf(acc[nt][0]);
    u16 u1 = f2bf(acc[nt][1]);
    u16 u2 = f2bf(acc[nt][2]);
    u16 u3 = f2bf(acc[nt][3]);
    dst[(size_t)(R0 + 0) * 256 + col] = u0;
    dst[(size_t)(R0 + 1) * 256 + col] = u1;
    dst[(size_t)(R0 + 2) * 256 + col] = u2;
    dst[(size_t)(R0 + 3) * 256 + col] = u3;
    if (src) {
      const int bb = R0 >> 11;
      const int mm = R0 & 2047;
      us4 pk;
      pk[0] = u0; pk[1] = u1; pk[2] = u2; pk[3] = u3;
      *(us4*)&kcol[((size_t)bb * 256 + col) * 2048 + mm] = pk;
    }
  }
}

// ---------------------------------------------------------------------------
// Kernel 2: row-sum pass (z=8, grid 2048 = 8 blocks/CU; XCD pin b = bid&7).
// ---------------------------------------------------------------------------
__global__ __launch_bounds__(256) void attn_sum_kernel(
    const u16* __restrict__ qb, const u16* __restrict__ krow,
    const int* __restrict__ mlens, const int* __restrict__ qlens,
    float* __restrict__ psum_p)
{
  __shared__ u16 kr[32 * 264];

  const int tid = threadIdx.x;
  const int w = tid >> 6;
  const int l = tid & 63;
  const int lr = l & 15;
  const int lh = l >> 4;
  const int bid = blockIdx.x;
  const int b = bid & 7;                    // XCD pin
  const int q0 = ((bid >> 3) & 31) * 64;
  const int ms = bid >> 8;                  // 0..7
  const int m_base = ms * 256;
  const int mlen = mlens[b];
  const int qlen = qlens[b];
  const int qrow0 = q0 + w * 16 + lh * 4;

  s8v qf[8];
  {
    const u16* qp = qb + ((size_t)b * 2048 + q0 + w * 16 + lr) * 256 + lh * 8;
#pragma unroll
    for (int s = 0; s < 8; ++s) qf[s] = *(const s8v*)(qp + s * 32);
  }

  float psum[4] = {0.f, 0.f, 0.f, 0.f};
  const float C2 = 0.09016844005556021f;  // log2(e)/16

  for (int mo = 0; mo < 256; mo += 32) {
    const int m0 = m_base + mo;
#pragma unroll
    for (int i = 0; i < 4; ++i) {
      const int idx = i * 256 + tid;
      const int m = idx >> 5, G = idx & 31;
      uint4 v = *(const uint4*)(krow + (((size_t)b * 2048 + m0 + m) << 8) + G * 8);
      *(uint4*)&kr[m * 264 + G * 8] = v;
    }
    __syncthreads();

    f4v sacc[2];
    sacc[0] = f4v{0.f, 0.f, 0.f, 0.f};
    sacc[1] = f4v{0.f, 0.f, 0.f, 0.f};
#pragma unroll
    for (int s = 0; s < 8; ++s) {
#pragma unroll
      for (int f = 0; f < 2; ++f) {
        const s8v bf = *(const s8v*)&kr[(f * 16 + lr) * 264 + s * 32 + lh * 8];
        sacc[f] = __builtin_amdgcn_mfma_f32_16x16x32_bf16(qf[s], bf, sacc[f], 0, 0, 0);
      }
    }
#pragma unroll
    for (int f = 0; f < 2; ++f) {
      const int m = m0 + f * 16 + lr;
      const bool vm = m < mlen;
#pragma unroll
      for (int r = 0; r < 4; ++r) {
        float p = exp2f(sacc[f][r] * C2);
        if (!vm) p = 0.f;
        if (qrow0 + r >= qlen) p = 1.f;
        psum[r] += p;
      }
    }
    __syncthreads();
  }

#pragma unroll
  for (int r = 0; r < 4; ++r) {
    float v = psum[r];
    v += __shfl_xor(v, 1);
    v += __shfl_xor(v, 2);
    v += __shfl_xor(v, 4);
    v += __shfl_xor(v, 8);
    psum[r] = v;
  }
  if (lr == 0) {
#pragma unroll
    for (int r = 0; r < 4; ++r)
      psum_p[ms * 16384 + b * 2048 + qrow0 + r] = psum[r];
  }
}

// ---------------------------------------------------------------------------
// Kernel 3: write pass (z=2, 32-m tiles, 42.5 KB LDS, XCD pin; inv sums 8
// psum partials). The 8x-measured local optimum geometry.
// ---------------------------------------------------------------------------
__global__ __launch_bounds__(256) void attn_wr_kernel(
    const u16* __restrict__ qb, const u16* __restrict__ krow,
    const u16* __restrict__ kcol, const int* __restrict__ mlens,
    const int* __restrict__ qlens, const float* __restrict__ psum_p,
    float* __restrict__ out_align, float* __restrict__ out_ctx,
    float* __restrict__ octx1)
{
  __shared__ u16 kr[32 * 264];
  __shared__ u16 kc[256 * 40];
  __shared__ u16 pl[4 * 16 * 40];

  const int tid = threadIdx.x;
  const int w = tid >> 6;
  const int l = tid & 63;
  const int lr = l & 15;
  const int lh = l >> 4;
  const int bid = blockIdx.x;
  const int b = bid & 7;                    // XCD pin
  const int q0 = ((bid >> 3) & 31) * 64;
  const int mh = bid >> 8;                  // 0..1
  const int m_base = mh * 1024;
  const int mlen = mlens[b];
  const int qlen = qlens[b];
  const int qrow0 = q0 + w * 16 + lh * 4;

  s8v qf[8];
  {
    const u16* qp = qb + ((size_t)b * 2048 + q0 + w * 16 + lr) * 256 + lh * 8;
#pragma unroll
    for (int s = 0; s < 8; ++s) qf[s] = *(const s8v*)(qp + s * 32);
  }

  float inv[4];
#pragma unroll
  for (int r = 0; r < 4; ++r) {
    const int q = b * 2048 + qrow0 + r;
    float s = 0.f;
#pragma unroll
    for (int j = 0; j < 8; ++j) s += psum_p[j * 16384 + q];
    inv[r] = 1.0f / s;
  }

  f4v oacc[16];
#pragma unroll
  for (int i = 0; i < 16; ++i) oacc[i] = f4v{0.f, 0.f, 0.f, 0.f};

  const float C2 = 0.09016844005556021f;  // log2(e)/16

  for (int mo = 0; mo < 1024; mo += 32) {
    const int m0 = m_base + mo;
#pragma unroll
    for (int i = 0; i < 4; ++i) {
      const int idx = i * 256 + tid;
      const int m = idx >> 5, G = idx & 31;
      uint4 v = *(const uint4*)(krow + (((size_t)b * 2048 + m0 + m) << 8) + G * 8);
      *(uint4*)&kr[m * 264 + G * 8] = v;
      const int a2 = idx >> 2, gm = idx & 3;
      uint4 v2 = *(const uint4*)(kcol + (((size_t)b * 256 + a2) << 11) + m0 + gm * 8);
      *(uint4*)&kc[a2 * 40 + gm * 8] = v2;
    }
    __syncthreads();

    f4v sacc[2];
    sacc[0] = f4v{0.f, 0.f, 0.f, 0.f};
    sacc[1] = f4v{0.f, 0.f, 0.f, 0.f};
#pragma unroll
    for (int s = 0; s < 8; ++s) {
#pragma unroll
      for (int f = 0; f < 2; ++f) {
        const s8v bf = *(const s8v*)&kr[(f * 16 + lr) * 264 + s * 32 + lh * 8];
        sacc[f] = __builtin_amdgcn_mfma_f32_16x16x32_bf16(qf[s], bf, sacc[f], 0, 0, 0);
      }
    }

#pragma unroll
    for (int f = 0; f < 2; ++f) {
      const int m = m0 + f * 16 + lr;
      const bool vm = m < mlen;
#pragma unroll
      for (int r = 0; r < 4; ++r) {
        const int q = qrow0 + r;
        float p = exp2f(sacc[f][r] * C2);
        if (!vm) p = 0.f;
        if (q >= qlen) p = 1.f;
        const float pn = p * inv[r];
        __builtin_nontemporal_store(pn, &out_align[((size_t)b * 2048 + q) * 2048 + m]);
        pl[w * 640 + (lh * 4 + r) * 40 + f * 16 + lr] = f2bf(pn);
      }
    }

    const s8v pa = *(const s8v*)&pl[w * 640 + lr * 40 + lh * 8];
#pragma unroll
    for (int at = 0; at < 16; ++at) {
      const s8v vf = *(const s8v*)&kc[(at * 16 + lr) * 40 + lh * 8];
      oacc[at] = __builtin_amdgcn_mfma_f32_16x16x32_bf16(pa, vf, oacc[at], 0, 0, 0);
    }
    __syncthreads();
  }

  float* __restrict__ dst = mh ? octx1 : out_ctx;
#pragma unroll
  for (int at = 0; at < 16; ++at) {
    const int a = at * 16 + lr;
#pragma unroll
    for (int r = 0; r < 4; ++r) {
      __builtin_nontemporal_store(oacc[at][r],
          &dst[((size_t)b * 2048 + qrow0 + r) * 256 + a]);
    }
  }
}

// ---------------------------------------------------------------------------
// Kernel 4: out_ctx += octx1
// ---------------------------------------------------------------------------
__global__ __launch_bounds__(256) void combine_kernel(
    float* __restrict__ out_ctx, const float* __restrict__ octx1)
{
  const size_t i = (size_t)blockIdx.x * 256 + threadIdx.x;
  float4 a = ((const float4*)out_ctx)[i];
  float4 c = ((const float4*)octx1)[i];
  a.x += c.x; a.y += c.y; a.z += c.z; a.w += c.w;
  ((float4*)out_ctx)[i] = a;
}

extern "C" void kernel_launch(void* const* d_in, const int* in_sizes, int n_in,
                              void* d_out, int out_size, void* d_ws, size_t ws_size,
                              hipStream_t stream) {
  const float* inputs = (const float*)d_in[0];   // [8,2048,512]
  const float* memory = (const float*)d_in[1];   // [8,2048,512]
  const int* mlens    = (const int*)d_in[2];     // [8]
  const int* qlens    = (const int*)d_in[3];     // [8]
  const float* Wq     = (const float*)d_in[4];   // [512,256]
  const float* Wk     = (const float*)d_in[5];   // [512,256]
  (void)in_sizes; (void)n_in; (void)out_size; (void)ws_size;

  u16* wsu = (u16*)d_ws;
  u16* qb   = wsu;                        // 4194304 u16 (8 MB)
  u16* krow = wsu + 4194304;              // 4194304 u16 (8 MB)
  u16* kcol = wsu + 8388608;              // 4194304 u16 (8 MB)
  float* psum_p = (float*)(wsu + 12582912);   // 8*16384 f32 (512 KB)
  float* octx1  = (float*)(wsu + 12845056);   // 4194304 f32 (16.8 MB)

  float* out_ctx = (float*)d_out;             // [8,2048,256]
  float* out_align = out_ctx + 4194304;       // [8,2048,2048]

  proj_kernel<<<dim3(256, 4, 2), dim3(256), 0, stream>>>(
      inputs, memory, Wq, Wk, qb, krow, kcol);
  attn_sum_kernel<<<dim3(2048), dim3(256), 0, stream>>>(
      qb, krow, mlens, qlens, psum_p);
  attn_wr_kernel<<<dim3(512), dim3(256), 0, stream>>>(
      qb, krow, kcol, mlens, qlens, psum_p, out_align, out_ctx, octx1);
  combine_kernel<<<dim3(4096), dim3(256), 0, stream>>>(out_ctx, octx1);
}